// Round 11
// baseline (199.925 us; speedup 1.0000x reference)
//
#include <hip/hip_runtime.h>

// Problem constants (fixed by setup_inputs)
#define Bsz 512
#define Tsz 12
#define Dsz 1024
#define Osz 512
#define Mrows (Bsz * Tsz)          // 6144 flattened rows
#define LIN_ELEMS (Mrows * Osz)    // 3145728
#define LIN_BYTES ((size_t)LIN_ELEMS * 4)
#define CNT_BYTES 2048
#define LIST_BYTES (512 * 512 * 4)

typedef unsigned short u16;
typedef short s16x8 __attribute__((ext_vector_type(8)));
typedef u16 u16x4 __attribute__((ext_vector_type(4)));
typedef float f32x4 __attribute__((ext_vector_type(4)));

// RNE float -> bf16 (bit pattern)
__device__ __forceinline__ u16 bfh(float f) {
    unsigned u = __float_as_uint(f);
    return (u16)((u + 0x7FFFu + ((u >> 16) & 1u)) >> 16);
}

// ---------------- K1: bf16x3-split MFMA GEMM 6144x512x1024 ----------------
// 128x128 tile, BK=32, 256 thr = 4 waves (2x2), wave = 64x64 = 4x4 rep of 16x16x32.
// acc += Ah*Bh + Ah*Bl + Al*Bh  (lo*lo dropped: <=2^-18 rel).
// LDS: k-major u16 tiles, row stride 40 u16 = 80B (16B-aligned b128 frags, 8-bank spread).
#define STRm 40
#define SEG (128 * STRm)          // 5120 u16 per tile segment (Ah|Al|Bh|Bl)
#define BUFU (4 * SEG)            // 20480 u16 per buffer; x2 dbuf = 81920 B

__global__ __launch_bounds__(256, 2) void gemm_mfma(
    const float* __restrict__ x,     // (6144, 1024)
    const float* __restrict__ Wm,    // (512, 1024)
    float* __restrict__ lin,         // ws: (2, 6144, 512)
    int nk)                          // K-steps (of 32) per split
{
    __shared__ u16 smem[2 * BUFU];   // 81920 B
    const int tid  = threadIdx.x;
    const int lane = tid & 63;
    const int wv   = tid >> 6;       // wave 0..3
    const int wm   = wv >> 1;        // wave M half
    const int wn   = wv & 1;         // wave N half
    const int l15  = lane & 15;
    const int g    = lane >> 4;      // k-group 0..3

    const int m0 = blockIdx.x * 128;
    const int n0 = blockIdx.y * 128;
    const int kbase = blockIdx.z * nk * 32;
    float* dst = lin + (size_t)blockIdx.z * LIN_ELEMS;

    const float* Ab = x  + (size_t)m0 * Dsz + kbase;
    const float* Wb = Wm + (size_t)n0 * Dsz + kbase;

    // staging: 128 rows x 8 float4 = 1024 quads each for A and W -> 4/thread each
    int g4[4], su[4];
#pragma unroll
    for (int i = 0; i < 4; ++i) {
        int f = tid + 256 * i;
        int row = f >> 3, c4 = f & 7;
        g4[i] = row * Dsz + c4 * 4;
        su[i] = row * STRm + c4 * 4;     // u16 units; byte = row*80 + c4*8 (8B aligned)
    }

    // MFMA fragment offsets (u16 units, relative to buffer base)
    // A: row = wm*64 + m*16 + (lane&15), k = (lane>>4)*8 + j  [m156-pattern]
    int aoff[4], boff[4];
#pragma unroll
    for (int m = 0; m < 4; ++m)
        aoff[m] = (wm * 64 + m * 16 + l15) * STRm + g * 8;
#pragma unroll
    for (int n = 0; n < 4; ++n)
        boff[n] = (wn * 64 + n * 16 + l15) * STRm + g * 8;

    f32x4 acc[4][4];
#pragma unroll
    for (int m = 0; m < 4; ++m)
#pragma unroll
        for (int n = 0; n < 4; ++n) acc[m][n] = (f32x4)0.0f;

    // prologue: stage K-step 0 into buffer 0
    {
        float4 ra[4], rw[4];
#pragma unroll
        for (int i = 0; i < 4; ++i) ra[i] = *reinterpret_cast<const float4*>(Ab + g4[i]);
#pragma unroll
        for (int i = 0; i < 4; ++i) rw[i] = *reinterpret_cast<const float4*>(Wb + g4[i]);
#pragma unroll
        for (int i = 0; i < 4; ++i) {
            float4 v = ra[i];
            u16 h0 = bfh(v.x), h1 = bfh(v.y), h2 = bfh(v.z), h3 = bfh(v.w);
            u16 l0 = bfh(v.x - __uint_as_float((unsigned)h0 << 16));
            u16 l1 = bfh(v.y - __uint_as_float((unsigned)h1 << 16));
            u16 l2 = bfh(v.z - __uint_as_float((unsigned)h2 << 16));
            u16 l3 = bfh(v.w - __uint_as_float((unsigned)h3 << 16));
            *reinterpret_cast<u16x4*>(smem + su[i])       = (u16x4){h0, h1, h2, h3};
            *reinterpret_cast<u16x4*>(smem + SEG + su[i]) = (u16x4){l0, l1, l2, l3};
            v = rw[i];
            h0 = bfh(v.x); h1 = bfh(v.y); h2 = bfh(v.z); h3 = bfh(v.w);
            l0 = bfh(v.x - __uint_as_float((unsigned)h0 << 16));
            l1 = bfh(v.y - __uint_as_float((unsigned)h1 << 16));
            l2 = bfh(v.z - __uint_as_float((unsigned)h2 << 16));
            l3 = bfh(v.w - __uint_as_float((unsigned)h3 << 16));
            *reinterpret_cast<u16x4*>(smem + 2 * SEG + su[i]) = (u16x4){h0, h1, h2, h3};
            *reinterpret_cast<u16x4*>(smem + 3 * SEG + su[i]) = (u16x4){l0, l1, l2, l3};
        }
    }
    __syncthreads();

    int cur = 0;
    for (int k0i = 0; k0i < nk; ++k0i) {
        float4 ra[4], rw[4];
        const bool more = (k0i < nk - 1);
        if (more) {
            const int k0n = (k0i + 1) * 32;
#pragma unroll
            for (int i = 0; i < 4; ++i) ra[i] = *reinterpret_cast<const float4*>(Ab + g4[i] + k0n);
#pragma unroll
            for (int i = 0; i < 4; ++i) rw[i] = *reinterpret_cast<const float4*>(Wb + g4[i] + k0n);
        }

        // ---- compute: 16 b128 frag reads + 48 MFMA ----
        const u16* bs = smem + cur * BUFU;
        s16x8 ah[4], al[4], bh[4], bl[4];
#pragma unroll
        for (int m = 0; m < 4; ++m) {
            ah[m] = *reinterpret_cast<const s16x8*>(bs + aoff[m]);
            al[m] = *reinterpret_cast<const s16x8*>(bs + SEG + aoff[m]);
        }
#pragma unroll
        for (int n = 0; n < 4; ++n) {
            bh[n] = *reinterpret_cast<const s16x8*>(bs + 2 * SEG + boff[n]);
            bl[n] = *reinterpret_cast<const s16x8*>(bs + 3 * SEG + boff[n]);
        }
#pragma unroll
        for (int m = 0; m < 4; ++m)
#pragma unroll
            for (int n = 0; n < 4; ++n) {
                acc[m][n] = __builtin_amdgcn_mfma_f32_16x16x32_bf16(ah[m], bh[n], acc[m][n], 0, 0, 0);
                acc[m][n] = __builtin_amdgcn_mfma_f32_16x16x32_bf16(ah[m], bl[n], acc[m][n], 0, 0, 0);
                acc[m][n] = __builtin_amdgcn_mfma_f32_16x16x32_bf16(al[m], bh[n], acc[m][n], 0, 0, 0);
            }

        if (more) {
            u16* nt = smem + (cur ^ 1) * BUFU;
#pragma unroll
            for (int i = 0; i < 4; ++i) {
                float4 v = ra[i];
                u16 h0 = bfh(v.x), h1 = bfh(v.y), h2 = bfh(v.z), h3 = bfh(v.w);
                u16 l0 = bfh(v.x - __uint_as_float((unsigned)h0 << 16));
                u16 l1 = bfh(v.y - __uint_as_float((unsigned)h1 << 16));
                u16 l2 = bfh(v.z - __uint_as_float((unsigned)h2 << 16));
                u16 l3 = bfh(v.w - __uint_as_float((unsigned)h3 << 16));
                *reinterpret_cast<u16x4*>(nt + su[i])       = (u16x4){h0, h1, h2, h3};
                *reinterpret_cast<u16x4*>(nt + SEG + su[i]) = (u16x4){l0, l1, l2, l3};
                v = rw[i];
                h0 = bfh(v.x); h1 = bfh(v.y); h2 = bfh(v.z); h3 = bfh(v.w);
                l0 = bfh(v.x - __uint_as_float((unsigned)h0 << 16));
                l1 = bfh(v.y - __uint_as_float((unsigned)h1 << 16));
                l2 = bfh(v.z - __uint_as_float((unsigned)h2 << 16));
                l3 = bfh(v.w - __uint_as_float((unsigned)h3 << 16));
                *reinterpret_cast<u16x4*>(nt + 2 * SEG + su[i]) = (u16x4){h0, h1, h2, h3};
                *reinterpret_cast<u16x4*>(nt + 3 * SEG + su[i]) = (u16x4){l0, l1, l2, l3};
            }
            __syncthreads();
            cur ^= 1;
        }
    }

    // epilogue: C/D layout (m89): col = lane&15, row = (lane>>4)*4 + reg
#pragma unroll
    for (int m = 0; m < 4; ++m)
#pragma unroll
        for (int n = 0; n < 4; ++n) {
            const int rbase = m0 + wm * 64 + m * 16 + g * 4;
            const int cg    = n0 + wn * 64 + n * 16 + l15;
#pragma unroll
            for (int j = 0; j < 4; ++j)
                dst[(size_t)(rbase + j) * Osz + cg] = acc[m][n][j];
        }
}

// ---------------- K2: dynamics + margin flag (LDS counter, no memset) ----------------
#define MARGIN 1e-4f

template <int NSPLIT>
__global__ __launch_bounds__(256) void dyn_flag(
    const float* __restrict__ lin,   // ws: (NSPLIT, 6144, 512)
    const float* __restrict__ bias,  // (512)
    float* __restrict__ out,         // (512, 512)
    int* __restrict__ cnt,           // ws: (512)
    int* __restrict__ list)          // ws: (512, 512)
{
    __shared__ int lcnt;
    __shared__ int llist[Osz];
    const int b   = blockIdx.x;
    const int tid = threadIdx.x;
    if (tid == 0) lcnt = 0;
    __syncthreads();

    const int o = tid * 2;
    {
        float2 part[Tsz][NSPLIT];
#pragma unroll
        for (int t = 0; t < Tsz; ++t)
#pragma unroll
            for (int s = 0; s < NSPLIT; ++s)
                part[t][s] = *reinterpret_cast<const float2*>(
                    lin + (size_t)s * LIN_ELEMS + (size_t)(b * Tsz + t) * Osz + o);

        const float2 bv = *reinterpret_cast<const float2*>(bias + o);
        float lax[Tsz], lay[Tsz];
#pragma unroll
        for (int t = 0; t < Tsz; ++t) {
            float sx = bv.x, sy = bv.y;
#pragma unroll
            for (int s = 0; s < NSPLIT; ++s) { sx += part[t][s].x; sy += part[t][s].y; }
            lax[t] = sx; lay[t] = sy;
        }

        float vx = 0.0f, sxx = 0.0f, mx = 1e30f, cfx = 0.0f;
        float vy = 0.0f, syy = 0.0f, my = 1e30f, cfy = 0.0f;
        for (int oi = 0; oi < Tsz; ++oi) {
            float cx = 0.0f, cy = 0.0f;
#pragma unroll
            for (int t = 0; t < Tsz; ++t) {
                vx = vx * 0.2f * (1.0f - sxx) + lax[t];
                vy = vy * 0.2f * (1.0f - syy) + lay[t];
                mx = fminf(mx, fabsf(vx - 0.5f));
                my = fminf(my, fabsf(vy - 0.5f));
                sxx = (vx > 0.5f) ? 1.0f : 0.0f;
                syy = (vy > 0.5f) ? 1.0f : 0.0f;
                cx += sxx; cy += syy;
            }
            cfx = cx; cfy = cy;
        }
        float2 o2; o2.x = cfx; o2.y = cfy;
        *reinterpret_cast<float2*>(out + (size_t)b * Osz + o) = o2;
        if (mx < MARGIN) { int sl = atomicAdd(&lcnt, 1); llist[sl] = o; }
        if (my < MARGIN) { int sl = atomicAdd(&lcnt, 1); llist[sl] = o + 1; }
    }
    __syncthreads();

    const int n = lcnt;
    if (tid == 0) cnt[b] = n;                 // always write (ws is poisoned)
    for (int i = tid; i < n; i += 256) list[b * 512 + i] = llist[i];
}

// ---------------- K3: exact fp64 recompute for flagged pairs ----------------
__global__ __launch_bounds__(512) void fix_k(
    const float* __restrict__ x, const float* __restrict__ Wm,
    const float* __restrict__ bias,
    const int* __restrict__ cnt, const int* __restrict__ list,
    float* __restrict__ out)
{
    __shared__ __align__(16) float xs[Tsz * Dsz];   // 48 KB
    const int b   = blockIdx.x;
    const int tid = threadIdx.x;
    const int n   = cnt[b];
    if (n == 0) return;

    const float* xb = x + (size_t)b * Tsz * Dsz;
    for (int i = tid; i < Tsz * Dsz / 4; i += 512)
        reinterpret_cast<float4*>(xs)[i] = reinterpret_cast<const float4*>(xb)[i];
    __syncthreads();

    const int wv = tid >> 6;   // 8 waves
    const int l  = tid & 63;
    for (int fi = wv; fi < n; fi += 8) {
        const int oo = list[b * 512 + fi];
        const float* wr = Wm + (size_t)oo * Dsz + l * 16;
        double dot[Tsz];
#pragma unroll
        for (int t = 0; t < Tsz; ++t) dot[t] = 0.0;
#pragma unroll
        for (int c4 = 0; c4 < 4; ++c4) {
            float4 w4 = *reinterpret_cast<const float4*>(wr + c4 * 4);
            const double w0 = (double)w4.x, w1 = (double)w4.y,
                         w2 = (double)w4.z, w3 = (double)w4.w;
#pragma unroll
            for (int t = 0; t < Tsz; ++t) {
                float4 x4 = *reinterpret_cast<const float4*>(xs + t * Dsz + l * 16 + c4 * 4);
                double d = dot[t];
                d = fma((double)x4.x, w0, d);
                d = fma((double)x4.y, w1, d);
                d = fma((double)x4.z, w2, d);
                dot[t] = fma((double)x4.w, w3, d);
            }
        }
#pragma unroll
        for (int off = 32; off; off >>= 1)
#pragma unroll
            for (int t = 0; t < Tsz; ++t)
                dot[t] += __shfl_down(dot[t], off);
        if (l == 0) {
            const double bvd = (double)bias[oo];
            double v = 0.0, s = 0.0, c = 0.0;
            for (int oi = 0; oi < Tsz; ++oi) {
                c = 0.0;
#pragma unroll
                for (int t = 0; t < Tsz; ++t) {
                    v = v * 0.2 * (1.0 - s) + (dot[t] + bvd);
                    s = (v > 0.5) ? 1.0 : 0.0;
                    c += s;
                }
            }
            out[(size_t)b * Osz + oo] = (float)c;
        }
    }
}

// ---------------- Fallback: proven round-1 fused fp64 kernel (ws too small) ----------------
#define F_AST 100
#define F_WST 68
#define F_BUFST 65
#define F_ABYTES (32 * F_AST * 4)

__global__ __launch_bounds__(192) void snn_fused_fb(
    const float* __restrict__ x, const float* __restrict__ Wm,
    const float* __restrict__ bias, float* __restrict__ out)
{
    __shared__ __align__(16) char smem[96 * F_BUFST * 8];
    float*  AsT = reinterpret_cast<float*>(smem);
    float*  WsT = reinterpret_cast<float*>(smem + F_ABYTES);
    double* buf = reinterpret_cast<double*>(smem);

    const int tid = threadIdx.x;
    const int ty  = tid >> 4;
    const int tx  = tid & 15;
    const int n0 = blockIdx.x * 64;
    const int b0 = blockIdx.y * 8;
    const int r0 = b0 * Tsz;

    double acc[8][4];
#pragma unroll
    for (int i = 0; i < 8; ++i)
#pragma unroll
        for (int j = 0; j < 4; ++j) acc[i][j] = 0.0;

    const float* Abase = x  + (size_t)r0 * Dsz;
    const float* Wbase = Wm + (size_t)n0 * Dsz;

    for (int k0 = 0; k0 < Dsz; k0 += 32) {
        __syncthreads();
#pragma unroll
        for (int it = 0; it < 4; ++it) {
            int idx = tid + 192 * it;
            int row = idx >> 3, c4 = idx & 7;
            float4 v = *reinterpret_cast<const float4*>(Abase + (size_t)row * Dsz + k0 + c4 * 4);
            int kb = c4 * 4;
            AsT[(kb + 0) * F_AST + row] = v.x;
            AsT[(kb + 1) * F_AST + row] = v.y;
            AsT[(kb + 2) * F_AST + row] = v.z;
            AsT[(kb + 3) * F_AST + row] = v.w;
        }
#pragma unroll
        for (int it = 0; it < 3; ++it) {
            int idx = tid + 192 * it;
            if (idx < 512) {
                int row = idx >> 3, c4 = idx & 7;
                float4 v = *reinterpret_cast<const float4*>(Wbase + (size_t)row * Dsz + k0 + c4 * 4);
                int kb = c4 * 4;
                WsT[(kb + 0) * F_WST + row] = v.x;
                WsT[(kb + 1) * F_WST + row] = v.y;
                WsT[(kb + 2) * F_WST + row] = v.z;
                WsT[(kb + 3) * F_WST + row] = v.w;
            }
        }
        __syncthreads();
#pragma unroll 4
        for (int kk = 0; kk < 32; ++kk) {
            const float* ar = &AsT[kk * F_AST + ty * 8];
            float4 a0 = *reinterpret_cast<const float4*>(ar);
            float4 a1 = *reinterpret_cast<const float4*>(ar + 4);
            float4 w0 = *reinterpret_cast<const float4*>(&WsT[kk * F_WST + tx * 4]);
            double ad[8] = {(double)a0.x, (double)a0.y, (double)a0.z, (double)a0.w,
                            (double)a1.x, (double)a1.y, (double)a1.z, (double)a1.w};
            double wd[4] = {(double)w0.x, (double)w0.y, (double)w0.z, (double)w0.w};
#pragma unroll
            for (int i = 0; i < 8; ++i)
#pragma unroll
                for (int j = 0; j < 4; ++j)
                    acc[i][j] = fma(ad[i], wd[j], acc[i][j]);
        }
    }
    __syncthreads();
#pragma unroll
    for (int i = 0; i < 8; ++i)
#pragma unroll
        for (int j = 0; j < 4; ++j)
            buf[(ty * 8 + i) * F_BUFST + (tx * 4 + j)] = acc[i][j];
    __syncthreads();

    for (int idx = tid; idx < 512; idx += 192) {
        int bl = idx >> 6, ol = idx & 63;
        double bv = (double)bias[n0 + ol];
        double la[Tsz];
#pragma unroll
        for (int t = 0; t < Tsz; ++t)
            la[t] = buf[(bl * Tsz + t) * F_BUFST + ol] + bv;
        double v = 0.0, s = 0.0;
        float cnt = 0.0f;
        for (int oi = 0; oi < Tsz; ++oi) {
            double c = 0.0;
#pragma unroll
            for (int t = 0; t < Tsz; ++t) {
                v = v * 0.2 * (1.0 - s) + la[t];
                s = (v > 0.5) ? 1.0 : 0.0;
                c += s;
            }
            cnt = (float)c;
        }
        out[(size_t)(b0 + bl) * Osz + (n0 + ol)] = cnt;
    }
}

extern "C" void kernel_launch(void* const* d_in, const int* in_sizes, int n_in,
                              void* d_out, int out_size, void* d_ws, size_t ws_size,
                              hipStream_t stream) {
    const float* x    = (const float*)d_in[0];   // (512,12,1024) fp32
    const float* Wm   = (const float*)d_in[1];   // (512,1024) fp32
    const float* bias = (const float*)d_in[2];   // (512) fp32
    float* out = (float*)d_out;                  // (512,512) fp32

    const size_t need = 2 * LIN_BYTES + CNT_BYTES + LIST_BYTES + 256;
    if (ws_size >= need) {
        float* lin  = (float*)d_ws;
        char*  base = (char*)d_ws + 2 * LIN_BYTES;
        int*   cnt  = (int*)base;
        int*   list = (int*)(base + CNT_BYTES);
        dim3 g1(Mrows / 128, Osz / 128, 2);      // (48, 4, 2) = 384 blocks
        hipLaunchKernelGGL(gemm_mfma, g1, dim3(256), 0, stream, x, Wm, lin, 16);
        hipLaunchKernelGGL((dyn_flag<2>), dim3(Bsz), dim3(256), 0, stream,
                           lin, bias, out, cnt, list);
        hipLaunchKernelGGL(fix_k, dim3(Bsz), dim3(512), 0, stream,
                           x, Wm, bias, cnt, list, out);
    } else {
        dim3 grid(Osz / 64, Bsz / 8);            // (8, 64)
        hipLaunchKernelGGL(snn_fused_fb, grid, dim3(192), 0, stream, x, Wm, bias, out);
    }
}

// Round 12
// 139.799 us; speedup vs baseline: 1.4301x; 1.4301x over previous
//
#include <hip/hip_runtime.h>

// Problem constants (fixed by setup_inputs)
#define Bsz 512
#define Tsz 12
#define Dsz 1024
#define Osz 512
#define Mrows (Bsz * Tsz)          // 6144
#define LIN_ELEMS (Mrows * Osz)    // 3145728
#define LIN_BYTES ((size_t)LIN_ELEMS * 4)         // 12582912
#define XS_BYTES  ((size_t)Mrows * Dsz * 2)       // 12582912 (one bf16 half of x)
#define WS_BYTES_ ((size_t)Osz * Dsz * 2)         // 1048576  (one bf16 half of W)
#define GLIST_CAP (Bsz * Osz)                     // 262144
#define GLIST_BYTES ((size_t)GLIST_CAP * 4)       // 1048576

typedef unsigned short u16;
typedef short s16x8 __attribute__((ext_vector_type(8)));
typedef u16 u16x4 __attribute__((ext_vector_type(4)));
typedef u16 u16x8 __attribute__((ext_vector_type(8)));
typedef float f32x4 __attribute__((ext_vector_type(4)));

__device__ __forceinline__ u16 bfh(float f) {   // RNE float -> bf16
    unsigned u = __float_as_uint(f);
    return (u16)((u + 0x7FFFu + ((u >> 16) & 1u)) >> 16);
}

// ---------------- K0: pre-split x,W into bf16 hi/lo (one-time, BW-bound) --------
__global__ __launch_bounds__(256) void presplit(
    const float* __restrict__ x, const float* __restrict__ Wm,
    u16* __restrict__ xh, u16* __restrict__ xl,
    u16* __restrict__ wh, u16* __restrict__ wl)
{
    const int NX4 = Mrows * Dsz / 4;   // 1572864
    const int NW4 = Osz * Dsz / 4;     // 131072
    const int stride = gridDim.x * blockDim.x;
    for (int i = blockIdx.x * blockDim.x + threadIdx.x; i < NX4 + NW4; i += stride) {
        const bool isx = (i < NX4);
        const int k = isx ? i : i - NX4;
        float4 v = isx ? reinterpret_cast<const float4*>(x)[k]
                       : reinterpret_cast<const float4*>(Wm)[k];
        u16 h0 = bfh(v.x), h1 = bfh(v.y), h2 = bfh(v.z), h3 = bfh(v.w);
        u16 l0 = bfh(v.x - __uint_as_float((unsigned)h0 << 16));
        u16 l1 = bfh(v.y - __uint_as_float((unsigned)h1 << 16));
        u16 l2 = bfh(v.z - __uint_as_float((unsigned)h2 << 16));
        u16 l3 = bfh(v.w - __uint_as_float((unsigned)h3 << 16));
        u16x4 H = {h0, h1, h2, h3}, L = {l0, l1, l2, l3};
        if (isx) { reinterpret_cast<u16x4*>(xh)[k] = H; reinterpret_cast<u16x4*>(xl)[k] = L; }
        else     { reinterpret_cast<u16x4*>(wh)[k] = H; reinterpret_cast<u16x4*>(wl)[k] = L; }
    }
}

// ---------------- K1: bf16x3 MFMA GEMM, 64x128 tile, splitk=1 ----------------
// 4 waves (2x2), wave tile 32x64 = 2x4 rep of 16x16x32. Frag/epilogue layouts
// identical to R11 (m89/m156). LDS row-major [row][STRm=40 u16] single buffer.
#define STRm 40
#define AH_OFF 0
#define AL_OFF 2560        // 64*40
#define BH_OFF 5120
#define BL_OFF 10240       // 5120 + 128*40
#define SM_U16 15360       // 30720 B

__global__ __launch_bounds__(256) void gemm_mfma(
    const u16* __restrict__ xh, const u16* __restrict__ xl,
    const u16* __restrict__ wh, const u16* __restrict__ wl,
    float* __restrict__ lin)
{
    __shared__ u16 sm[SM_U16];
    const int tid  = threadIdx.x;
    const int lane = tid & 63;
    const int wv   = tid >> 6;
    const int wm   = wv >> 1;        // M half (32 rows)
    const int wn   = wv & 1;         // N half (64 cols)
    const int l15  = lane & 15;
    const int g    = lane >> 4;      // k-group 0..3

    const int m0 = blockIdx.x * 64;
    const int n0 = blockIdx.y * 128;

    // staging: A 64x4=256 quads (1/thread/half), B 128x4=512 (2/thread/half)
    const int arow = tid >> 2, ak8 = tid & 3;
    const size_t agl = (size_t)(m0 + arow) * Dsz + ak8 * 8;
    const int    asl = arow * STRm + ak8 * 8;
    const size_t bgl0 = (size_t)(n0 + arow) * Dsz + ak8 * 8;        // rows 0..63
    const size_t bgl1 = (size_t)(n0 + arow + 64) * Dsz + ak8 * 8;   // rows 64..127
    const int    bsl0 = arow * STRm + ak8 * 8;
    const int    bsl1 = (arow + 64) * STRm + ak8 * 8;

    int aoff[2], boff[4];
#pragma unroll
    for (int m = 0; m < 2; ++m) aoff[m] = (wm * 32 + m * 16 + l15) * STRm + g * 8;
#pragma unroll
    for (int n = 0; n < 4; ++n) boff[n] = (wn * 64 + n * 16 + l15) * STRm + g * 8;

    f32x4 acc[2][4];
#pragma unroll
    for (int m = 0; m < 2; ++m)
#pragma unroll
        for (int n = 0; n < 4; ++n) acc[m][n] = (f32x4)0.0f;

    u16x8 rAh, rAl, rBh0, rBh1, rBl0, rBl1;
    // prologue load (K-step 0)
    rAh  = *reinterpret_cast<const u16x8*>(xh + agl);
    rAl  = *reinterpret_cast<const u16x8*>(xl + agl);
    rBh0 = *reinterpret_cast<const u16x8*>(wh + bgl0);
    rBh1 = *reinterpret_cast<const u16x8*>(wh + bgl1);
    rBl0 = *reinterpret_cast<const u16x8*>(wl + bgl0);
    rBl1 = *reinterpret_cast<const u16x8*>(wl + bgl1);

    for (int st = 0; st < 32; ++st) {
        __syncthreads();   // prior compute done before overwrite
        *reinterpret_cast<u16x8*>(sm + AH_OFF + asl)  = rAh;
        *reinterpret_cast<u16x8*>(sm + AL_OFF + asl)  = rAl;
        *reinterpret_cast<u16x8*>(sm + BH_OFF + bsl0) = rBh0;
        *reinterpret_cast<u16x8*>(sm + BH_OFF + bsl1) = rBh1;
        *reinterpret_cast<u16x8*>(sm + BL_OFF + bsl0) = rBl0;
        *reinterpret_cast<u16x8*>(sm + BL_OFF + bsl1) = rBl1;
        __syncthreads();

        if (st < 31) {     // issue next-step loads; latency hides under MFMAs
            const int k0 = (st + 1) * 32;
            rAh  = *reinterpret_cast<const u16x8*>(xh + agl + k0);
            rAl  = *reinterpret_cast<const u16x8*>(xl + agl + k0);
            rBh0 = *reinterpret_cast<const u16x8*>(wh + bgl0 + k0);
            rBh1 = *reinterpret_cast<const u16x8*>(wh + bgl1 + k0);
            rBl0 = *reinterpret_cast<const u16x8*>(wl + bgl0 + k0);
            rBl1 = *reinterpret_cast<const u16x8*>(wl + bgl1 + k0);
        }

        s16x8 ah[2], al[2], bh[4], bl[4];
#pragma unroll
        for (int m = 0; m < 2; ++m) {
            ah[m] = *reinterpret_cast<const s16x8*>(sm + AH_OFF + aoff[m]);
            al[m] = *reinterpret_cast<const s16x8*>(sm + AL_OFF + aoff[m]);
        }
#pragma unroll
        for (int n = 0; n < 4; ++n) {
            bh[n] = *reinterpret_cast<const s16x8*>(sm + BH_OFF + boff[n]);
            bl[n] = *reinterpret_cast<const s16x8*>(sm + BL_OFF + boff[n]);
        }
#pragma unroll
        for (int m = 0; m < 2; ++m)
#pragma unroll
            for (int n = 0; n < 4; ++n) {
                acc[m][n] = __builtin_amdgcn_mfma_f32_16x16x32_bf16(ah[m], bh[n], acc[m][n], 0, 0, 0);
                acc[m][n] = __builtin_amdgcn_mfma_f32_16x16x32_bf16(ah[m], bl[n], acc[m][n], 0, 0, 0);
                acc[m][n] = __builtin_amdgcn_mfma_f32_16x16x32_bf16(al[m], bh[n], acc[m][n], 0, 0, 0);
            }
    }

    // epilogue: C/D (m89): col = lane&15, row = (lane>>4)*4 + reg
#pragma unroll
    for (int m = 0; m < 2; ++m)
#pragma unroll
        for (int n = 0; n < 4; ++n) {
            const int rbase = m0 + wm * 32 + m * 16 + g * 4;
            const int col   = n0 + wn * 64 + n * 16 + l15;
#pragma unroll
            for (int j = 0; j < 4; ++j)
                lin[(size_t)(rbase + j) * Osz + col] = acc[m][n][j];
        }
}

// ---------------- K2: dynamics + margin flag -> global queue ----------------
// MARGIN: bf16x3+fp32-accum worst-case lin error ~2e-5 incl. 1.25x recurrence gain.
#define MARGIN 1e-4f

__global__ __launch_bounds__(256) void dyn_flag(
    const float* __restrict__ lin,   // (6144, 512)
    const float* __restrict__ bias,
    float* __restrict__ out,         // (512, 512)
    int* __restrict__ gcnt,
    int* __restrict__ glist)
{
    const int b   = blockIdx.x;
    const int tid = threadIdx.x;
    const int o   = tid * 2;

    float2 p[Tsz];
#pragma unroll
    for (int t = 0; t < Tsz; ++t)
        p[t] = *reinterpret_cast<const float2*>(lin + (size_t)(b * Tsz + t) * Osz + o);
    const float2 bv = *reinterpret_cast<const float2*>(bias + o);

    float lax[Tsz], lay[Tsz];
#pragma unroll
    for (int t = 0; t < Tsz; ++t) { lax[t] = p[t].x + bv.x; lay[t] = p[t].y + bv.y; }

    float vx = 0.0f, sxx = 0.0f, mx = 1e30f, cfx = 0.0f;
    float vy = 0.0f, syy = 0.0f, my = 1e30f, cfy = 0.0f;
    bool badx = false, bady = false;
    for (int oi = 0; oi < Tsz; ++oi) {
        float cx = 0.0f, cy = 0.0f;
#pragma unroll
        for (int t = 0; t < Tsz; ++t) {
            vx = vx * 0.2f * (1.0f - sxx) + lax[t];
            vy = vy * 0.2f * (1.0f - syy) + lay[t];
            badx |= !(fabsf(vx) < 1e30f);            // catches NaN/Inf
            bady |= !(fabsf(vy) < 1e30f);
            mx = fminf(mx, fabsf(vx - 0.5f));
            my = fminf(my, fabsf(vy - 0.5f));
            sxx = (vx > 0.5f) ? 1.0f : 0.0f;
            syy = (vy > 0.5f) ? 1.0f : 0.0f;
            cx += sxx; cy += syy;
        }
        cfx = cx; cfy = cy;
    }
    float2 o2; o2.x = cfx; o2.y = cfy;
    *reinterpret_cast<float2*>(out + (size_t)b * Osz + o) = o2;
    if (!(mx >= MARGIN) || badx) { int sl = atomicAdd(gcnt, 1); glist[sl] = (b << 9) | o; }
    if (!(my >= MARGIN) || bady) { int sl = atomicAdd(gcnt, 1); glist[sl] = (b << 9) | (o + 1); }
}

// ---------------- K3: exact fp64 recompute, ONE WAVE PER PAIR (global queue) -----
// No LDS, no per-batch blocks: cost scales with total flags, fully parallel.
__global__ __launch_bounds__(256) void fix_q(
    const float* __restrict__ x, const float* __restrict__ Wm,
    const float* __restrict__ bias,
    const int* __restrict__ gcnt, const int* __restrict__ glist,
    float* __restrict__ out)
{
    const int total = gcnt[0];
    const int gw = blockIdx.x * 4 + (threadIdx.x >> 6);   // 2048 waves
    const int l  = threadIdx.x & 63;

    for (int i = gw; i < total; i += 2048) {
        const int e = glist[i];
        const int b = e >> 9, o = e & 511;
        const float* xr = x  + (size_t)b * (Tsz * Dsz) + l * 16;
        const float* wr = Wm + (size_t)o * Dsz + l * 16;
        double dot[Tsz];
#pragma unroll
        for (int t = 0; t < Tsz; ++t) dot[t] = 0.0;
#pragma unroll
        for (int c4 = 0; c4 < 4; ++c4) {
            float4 w4 = *reinterpret_cast<const float4*>(wr + c4 * 4);
            const double w0 = (double)w4.x, w1 = (double)w4.y,
                         w2 = (double)w4.z, w3 = (double)w4.w;
#pragma unroll
            for (int t = 0; t < Tsz; ++t) {
                float4 x4 = *reinterpret_cast<const float4*>(xr + t * Dsz + c4 * 4);
                double d = dot[t];
                d = fma((double)x4.x, w0, d);
                d = fma((double)x4.y, w1, d);
                d = fma((double)x4.z, w2, d);
                dot[t] = fma((double)x4.w, w3, d);
            }
        }
#pragma unroll
        for (int off = 32; off; off >>= 1)
#pragma unroll
            for (int t = 0; t < Tsz; ++t)
                dot[t] += __shfl_down(dot[t], off);
        if (l == 0) {
            const double bvd = (double)bias[o];
            double v = 0.0, s = 0.0, c = 0.0;
            for (int oi = 0; oi < Tsz; ++oi) {
                c = 0.0;
#pragma unroll
                for (int t = 0; t < Tsz; ++t) {
                    v = v * 0.2 * (1.0 - s) + (dot[t] + bvd);
                    s = (v > 0.5) ? 1.0 : 0.0;
                    c += s;
                }
            }
            out[(size_t)b * Osz + o] = (float)c;
        }
    }
}

// ---------------- Fallback: proven round-1 fused fp64 kernel ----------------
#define F_AST 100
#define F_WST 68
#define F_BUFST 65
#define F_ABYTES (32 * F_AST * 4)

__global__ __launch_bounds__(192) void snn_fused_fb(
    const float* __restrict__ x, const float* __restrict__ Wm,
    const float* __restrict__ bias, float* __restrict__ out)
{
    __shared__ __align__(16) char smem[96 * F_BUFST * 8];
    float*  AsT = reinterpret_cast<float*>(smem);
    float*  WsT = reinterpret_cast<float*>(smem + F_ABYTES);
    double* buf = reinterpret_cast<double*>(smem);

    const int tid = threadIdx.x;
    const int ty  = tid >> 4;
    const int tx  = tid & 15;
    const int n0 = blockIdx.x * 64;
    const int b0 = blockIdx.y * 8;
    const int r0 = b0 * Tsz;

    double acc[8][4];
#pragma unroll
    for (int i = 0; i < 8; ++i)
#pragma unroll
        for (int j = 0; j < 4; ++j) acc[i][j] = 0.0;

    const float* Abase = x  + (size_t)r0 * Dsz;
    const float* Wbase = Wm + (size_t)n0 * Dsz;

    for (int k0 = 0; k0 < Dsz; k0 += 32) {
        __syncthreads();
#pragma unroll
        for (int it = 0; it < 4; ++it) {
            int idx = tid + 192 * it;
            int row = idx >> 3, c4 = idx & 7;
            float4 v = *reinterpret_cast<const float4*>(Abase + (size_t)row * Dsz + k0 + c4 * 4);
            int kb = c4 * 4;
            AsT[(kb + 0) * F_AST + row] = v.x;
            AsT[(kb + 1) * F_AST + row] = v.y;
            AsT[(kb + 2) * F_AST + row] = v.z;
            AsT[(kb + 3) * F_AST + row] = v.w;
        }
#pragma unroll
        for (int it = 0; it < 3; ++it) {
            int idx = tid + 192 * it;
            if (idx < 512) {
                int row = idx >> 3, c4 = idx & 7;
                float4 v = *reinterpret_cast<const float4*>(Wbase + (size_t)row * Dsz + k0 + c4 * 4);
                int kb = c4 * 4;
                WsT[(kb + 0) * F_WST + row] = v.x;
                WsT[(kb + 1) * F_WST + row] = v.y;
                WsT[(kb + 2) * F_WST + row] = v.z;
                WsT[(kb + 3) * F_WST + row] = v.w;
            }
        }
        __syncthreads();
#pragma unroll 4
        for (int kk = 0; kk < 32; ++kk) {
            const float* ar = &AsT[kk * F_AST + ty * 8];
            float4 a0 = *reinterpret_cast<const float4*>(ar);
            float4 a1 = *reinterpret_cast<const float4*>(ar + 4);
            float4 w0 = *reinterpret_cast<const float4*>(&WsT[kk * F_WST + tx * 4]);
            double ad[8] = {(double)a0.x, (double)a0.y, (double)a0.z, (double)a0.w,
                            (double)a1.x, (double)a1.y, (double)a1.z, (double)a1.w};
            double wd[4] = {(double)w0.x, (double)w0.y, (double)w0.z, (double)w0.w};
#pragma unroll
            for (int i = 0; i < 8; ++i)
#pragma unroll
                for (int j = 0; j < 4; ++j)
                    acc[i][j] = fma(ad[i], wd[j], acc[i][j]);
        }
    }
    __syncthreads();
#pragma unroll
    for (int i = 0; i < 8; ++i)
#pragma unroll
        for (int j = 0; j < 4; ++j)
            buf[(ty * 8 + i) * F_BUFST + (tx * 4 + j)] = acc[i][j];
    __syncthreads();

    for (int idx = tid; idx < 512; idx += 192) {
        int bl = idx >> 6, ol = idx & 63;
        double bv = (double)bias[n0 + ol];
        double la[Tsz];
#pragma unroll
        for (int t = 0; t < Tsz; ++t)
            la[t] = buf[(bl * Tsz + t) * F_BUFST + ol] + bv;
        double v = 0.0, s = 0.0;
        float cnt = 0.0f;
        for (int oi = 0; oi < Tsz; ++oi) {
            double c = 0.0;
#pragma unroll
            for (int t = 0; t < Tsz; ++t) {
                v = v * 0.2 * (1.0 - s) + la[t];
                s = (v > 0.5) ? 1.0 : 0.0;
                c += s;
            }
            cnt = (float)c;
        }
        out[(size_t)(b0 + bl) * Osz + (n0 + ol)] = cnt;
    }
}

extern "C" void kernel_launch(void* const* d_in, const int* in_sizes, int n_in,
                              void* d_out, int out_size, void* d_ws, size_t ws_size,
                              hipStream_t stream) {
    const float* x    = (const float*)d_in[0];   // (512,12,1024) fp32
    const float* Wm   = (const float*)d_in[1];   // (512,1024) fp32
    const float* bias = (const float*)d_in[2];   // (512) fp32
    float* out = (float*)d_out;                  // (512,512) fp32

    // ws layout
    const size_t off_lin   = 0;
    const size_t off_xh    = off_lin + LIN_BYTES;
    const size_t off_xl    = off_xh + XS_BYTES;
    const size_t off_wh    = off_xl + XS_BYTES;
    const size_t off_wl    = off_wh + WS_BYTES_;
    const size_t off_glist = off_wl + WS_BYTES_;
    const size_t off_gcnt  = off_glist + GLIST_BYTES;
    const size_t need      = off_gcnt + 64;      // ~40.9 MB (< R9-proven 50.3 MB)

    if (ws_size >= need) {
        char* base = (char*)d_ws;
        float* lin = (float*)(base + off_lin);
        u16* xh = (u16*)(base + off_xh);
        u16* xl = (u16*)(base + off_xl);
        u16* wh = (u16*)(base + off_wh);
        u16* wl = (u16*)(base + off_wl);
        int* glist = (int*)(base + off_glist);
        int* gcnt  = (int*)(base + off_gcnt);

        hipMemsetAsync(gcnt, 0, 64, stream);
        hipLaunchKernelGGL(presplit, dim3(2048), dim3(256), 0, stream,
                           x, Wm, xh, xl, wh, wl);
        hipLaunchKernelGGL(gemm_mfma, dim3(Mrows / 64, Osz / 128), dim3(256), 0, stream,
                           xh, xl, wh, wl, lin);
        hipLaunchKernelGGL(dyn_flag, dim3(Bsz), dim3(256), 0, stream,
                           lin, bias, out, gcnt, glist);
        hipLaunchKernelGGL(fix_q, dim3(512), dim3(256), 0, stream,
                           x, Wm, bias, gcnt, glist, out);
    } else {
        dim3 grid(Osz / 64, Bsz / 8);            // (8, 64)
        hipLaunchKernelGGL(snn_fused_fb, grid, dim3(192), 0, stream, x, Wm, bias, out);
    }
}